// Round 2
// baseline (5035.188 us; speedup 1.0000x reference)
//
#include <hip/hip_runtime.h>
#include <stdint.h>

// GCN layer: out = relu( segment_sum(vals * emb[cols], rows) @ W )
// Reordered: out = relu( segment_sum(vals * P[cols], rows) ), P = emb @ W.
// Bucket pipeline (RB=64 rows/bucket):
//   detect -> bucket hist/scan -> Wt bf16 -> P = emb@W (MFMA) ->
//   LDS-multisplit edges into buckets (coalesced-run writes, 1 atomic per
//   block*bucket) -> per-bucket LDS f32 accumulation + ReLU -> out.
// Replaces row-level CSR (hist/scan/scatter/agg): kills the 8x write
// amplification of random 8B CSR stores (203MB -> ~60MB) and all per-edge
// global atomics.

typedef unsigned short u16;
typedef __attribute__((ext_vector_type(8))) short short8v;  // 8 bf16
typedef __attribute__((ext_vector_type(4))) float f32x4;    // MFMA C/D

#define RBSH 6
#define RB 64            // rows per bucket
#define NBMAX 2048       // supports N <= 131072
#define MS_T 4096        // edges per multisplit tile
#define MS_PT 16         // edges per thread (256 threads)

__device__ __forceinline__ float b2f(u16 u) {
  union { unsigned i; float f; } x; x.i = ((unsigned)u) << 16; return x.f;
}
__device__ __forceinline__ u16 f2b(float f) {
  union { unsigned i; float f; } x; x.f = f;
  unsigned r = x.i + 0x7fffu + ((x.i >> 16) & 1u);
  return (u16)(r >> 16);
}

// ---- dtype detect: adj_vals ~ U[0,1). As f32 words, low16 uniform
// (>=0x3F80 ~75%). As packed bf16 pairs, low16 is bf16 in [0,1) -> <0x3F80.
__global__ void detect_k(const unsigned* __restrict__ valsw, int* __restrict__ flag) {
  __shared__ int cnt;
  if (threadIdx.x == 0) cnt = 0;
  __syncthreads();
  int c = 0;
  for (int i = threadIdx.x; i < 4096; i += 256) {
    unsigned w = valsw[i];
    if ((w & 0xFFFFu) >= 0x3F80u) c++;
  }
  atomicAdd(&cnt, c);
  __syncthreads();
  if (threadIdx.x == 0) *flag = (cnt < 1024) ? 1 : 0;
}

// ---------------- bucket histogram (LDS-staged) ----------------
__global__ __launch_bounds__(256) void bhist_k(const int* __restrict__ rows,
                                               int* __restrict__ bcounts, int E, int NB) {
  __shared__ int h[NBMAX];
  int tid = threadIdx.x;
  for (int b = tid; b < NB; b += 256) h[b] = 0;
  __syncthreads();
  for (int i = blockIdx.x * 256 + tid; i < E; i += gridDim.x * 256)
    atomicAdd(&h[rows[i] >> RBSH], 1);
  __syncthreads();
  for (int b = tid; b < NB; b += 256) {
    int c = h[b];
    if (c) atomicAdd(&bcounts[b], c);
  }
}

// ---------------- bucket exclusive scan (1 block) ----------------
__global__ __launch_bounds__(256) void bscan_k(const int* __restrict__ bcounts,
                                               int* __restrict__ boffs,
                                               int* __restrict__ bcursor, int NB) {
  __shared__ int part[256];
  int tid = threadIdx.x;
  int K = (NB + 255) >> 8;
  int lo = tid * K, hi = lo + K;
  if (hi > NB) hi = NB;
  if (lo > NB) lo = NB;
  int s = 0;
  for (int b = lo; b < hi; ++b) s += bcounts[b];
  part[tid] = s;
  __syncthreads();
  for (int o = 1; o < 256; o <<= 1) {
    int v = (tid >= o) ? part[tid - o] : 0;
    __syncthreads();
    part[tid] += v;
    __syncthreads();
  }
  int run = part[tid] - s;  // exclusive base for this thread's range
  for (int b = lo; b < hi; ++b) {
    int c = bcounts[b];
    boffs[b] = run;
    bcursor[b] = run;
    run += c;
  }
  if (tid == 255) boffs[NB] = part[255];
}

// ---------------- multisplit: tile-sort edges by bucket in LDS ----------------
// Entry: x = col | ((row & 63) << 17)  (col < 2^17), y = f32 bits of val.
template <bool BF16>
__global__ __launch_bounds__(256) void ms_k(const int* __restrict__ flag,
                                            const int* __restrict__ rows,
                                            const int* __restrict__ cols,
                                            const void* __restrict__ valsv,
                                            int* __restrict__ bcursor,
                                            int2* __restrict__ pack, int E, int NB) {
  if (*flag != (BF16 ? 1 : 0)) return;
  __shared__ int hist[NBMAX + 1];  // becomes exclusive prefix (lbase)
  __shared__ int gbase[NBMAX];
  __shared__ int part[256];
  __shared__ int2 buf[MS_T];
  __shared__ u16 brow[MS_T];
  int tid = threadIdx.x;
  int base = blockIdx.x * MS_T;

  for (int b = tid; b <= NB; b += 256) hist[b] = 0;
  __syncthreads();

  int bk[MS_PT], ofs[MS_PT], cl[MS_PT], vb[MS_PT];
#pragma unroll
  for (int i = 0; i < MS_PT; ++i) {
    int e = base + i * 256 + tid;
    if (e < E) {
      int r = rows[e];
      bk[i] = r >> RBSH;
      cl[i] = cols[e] | ((r & (RB - 1)) << 17);
      float v = BF16 ? b2f(((const u16*)valsv)[e]) : ((const float*)valsv)[e];
      vb[i] = __float_as_int(v);
      ofs[i] = atomicAdd(&hist[bk[i]], 1);
    } else {
      bk[i] = -1; ofs[i] = 0; cl[i] = 0; vb[i] = 0;
    }
  }
  __syncthreads();

  // two-level exclusive prefix of hist[0..NB) in place; hist[NB] = total
  int K = (NB + 255) >> 8;
  int lo = tid * K, hi = lo + K;
  if (hi > NB) hi = NB;
  if (lo > NB) lo = NB;
  int s = 0;
  for (int b = lo; b < hi; ++b) s += hist[b];
  part[tid] = s;
  __syncthreads();
  for (int o = 1; o < 256; o <<= 1) {
    int v = (tid >= o) ? part[tid - o] : 0;
    __syncthreads();
    part[tid] += v;
    __syncthreads();
  }
  int run = part[tid] - s;
  for (int b = lo; b < hi; ++b) {
    int c = hist[b];
    hist[b] = run;
    run += c;
  }
  if (tid == 255) hist[NB] = part[255];
  __syncthreads();

  // scatter to LDS (sorted by bucket) + reserve global ranges
#pragma unroll
  for (int i = 0; i < MS_PT; ++i) {
    if (bk[i] >= 0) {
      int slot = hist[bk[i]] + ofs[i];
      buf[slot] = make_int2(cl[i], vb[i]);
      brow[slot] = (u16)bk[i];
    }
  }
  for (int b = tid; b < NB; b += 256) {
    int c = hist[b + 1] - hist[b];
    if (c > 0) gbase[b] = atomicAdd(&bcursor[b], c);
  }
  __syncthreads();

  // coalesced-run copy out
  int tot = hist[NB];
  for (int i = tid; i < tot; i += 256) {
    int b = brow[i];
    pack[gbase[b] + (i - hist[b])] = buf[i];
  }
}

// ---------------- W -> bf16, transposed: Wt[n][k] = W[k][n] ----------------
template <bool BF16>
__global__ void wtr_k(const int* __restrict__ flag, const void* __restrict__ Wv,
                      u16* __restrict__ Wt) {
  if (*flag != (BF16 ? 1 : 0)) return;
  int i = blockIdx.x * 256 + threadIdx.x;  // 65536 total
  int n = i >> 8, k = i & 255;
  float w = BF16 ? b2f(((const u16*)Wv)[k * 256 + n]) : ((const float*)Wv)[k * 256 + n];
  Wt[n * 256 + k] = f2b(w);
}

// ---------------- P = emb @ W via MFMA bf16 (unchanged, verified) ----------------
template <bool BF16>
__global__ __launch_bounds__(256) void proj_k(const int* __restrict__ flag,
                                              const void* __restrict__ embv,
                                              const u16* __restrict__ Wt,
                                              u16* __restrict__ P, int N) {
  if (*flag != (BF16 ? 1 : 0)) return;
  int wave = threadIdx.x >> 6, lane = threadIdx.x & 63;
  int lr = lane & 15, lq = lane >> 4;
  int m0 = blockIdx.x * 64;
  int n0 = wave * 64;

  f32x4 acc[4][4];
#pragma unroll
  for (int mi = 0; mi < 4; ++mi)
#pragma unroll
    for (int ni = 0; ni < 4; ++ni) acc[mi][ni] = (f32x4)0.f;

  int arow[4];
#pragma unroll
  for (int mi = 0; mi < 4; ++mi) {
    int r = m0 + mi * 16 + lr;
    arow[mi] = r < N ? r : N - 1;
  }

  for (int ks = 0; ks < 8; ++ks) {
    int kb = ks * 32 + lq * 8;
    short8v a[4], b[4];
#pragma unroll
    for (int mi = 0; mi < 4; ++mi) {
      if (BF16) {
        a[mi] = *(const short8v*)((const u16*)embv + (size_t)arow[mi] * 256 + kb);
      } else {
        const float* p = (const float*)embv + (size_t)arow[mi] * 256 + kb;
        float4 x = *(const float4*)p;
        float4 y = *(const float4*)(p + 4);
        short8v t;
        t[0] = (short)f2b(x.x); t[1] = (short)f2b(x.y);
        t[2] = (short)f2b(x.z); t[3] = (short)f2b(x.w);
        t[4] = (short)f2b(y.x); t[5] = (short)f2b(y.y);
        t[6] = (short)f2b(y.z); t[7] = (short)f2b(y.w);
        a[mi] = t;
      }
    }
#pragma unroll
    for (int ni = 0; ni < 4; ++ni)
      b[ni] = *(const short8v*)(Wt + (size_t)(n0 + ni * 16 + lr) * 256 + kb);
#pragma unroll
    for (int mi = 0; mi < 4; ++mi)
#pragma unroll
      for (int ni = 0; ni < 4; ++ni)
        acc[mi][ni] = __builtin_amdgcn_mfma_f32_16x16x32_bf16(a[mi], b[ni], acc[mi][ni], 0, 0, 0);
  }

#pragma unroll
  for (int mi = 0; mi < 4; ++mi) {
    int rbase = m0 + mi * 16 + lq * 4;
#pragma unroll
    for (int ni = 0; ni < 4; ++ni) {
      int col = n0 + ni * 16 + lr;
#pragma unroll
      for (int r = 0; r < 4; ++r) {
        int row = rbase + r;
        if (row < N) P[(size_t)row * 256 + col] = f2b(acc[mi][ni][r]);
      }
    }
  }
}

// ---------------- per-bucket aggregation: LDS f32 accumulators ----------------
// acc layout phi(d) = (d&3)*64 + (d>>2): ds_add_f32 lanes hit banks 0..31
// 2-way (free); gather stays contiguous ushort4 per lane.
template <bool OUTBF16>
__global__ __launch_bounds__(512) void bagg_k(const int* __restrict__ flag,
                                              const u16* __restrict__ P,
                                              const int* __restrict__ boffs,
                                              const int2* __restrict__ pack,
                                              void* __restrict__ outv, int N) {
  if (*flag != (OUTBF16 ? 1 : 0)) return;
  __shared__ float acc[RB * 256];  // 64 KB
  int tid = threadIdx.x;
  int b = blockIdx.x;
  for (int i = tid; i < RB * 256; i += 512) acc[i] = 0.f;
  __syncthreads();

  int beg = boffs[b], end = boffs[b + 1];
  int w = tid >> 6, lane = tid & 63;
  const u16* pbase = P + lane * 4;

  for (int e8 = beg + w * 8; e8 < end; e8 += 64) {
    int nb = end - e8;
    if (nb > 8) nb = 8;
    int l7 = lane & 7;
    int sel = l7 < nb ? l7 : nb - 1;
    int2 q = pack[e8 + sel];
    ushort4 er[8]; int ro[8]; float vr[8];
#pragma unroll
    for (int k = 0; k < 8; ++k) {
      if (k < nb) {
        int x = __shfl(q.x, k);
        ro[k] = x >> 17;
        vr[k] = __int_as_float(__shfl(q.y, k));
        er[k] = *(const ushort4*)(pbase + (size_t)(x & 0x1FFFF) * 256);
      }
    }
#pragma unroll
    for (int k = 0; k < 8; ++k) {
      if (k < nb) {
        float v = vr[k];
        float* a = &acc[ro[k] * 256 + lane];
        atomicAdd(a +   0, v * b2f(er[k].x));
        atomicAdd(a +  64, v * b2f(er[k].y));
        atomicAdd(a + 128, v * b2f(er[k].z));
        atomicAdd(a + 192, v * b2f(er[k].w));
      }
    }
  }
  __syncthreads();

  // write out: dims {4*j4..4*j4+3} of row r live at acc[r*256 + j*64 + j4]
  int nbase = b * RB;
  for (int g = tid; g < RB * 64; g += 512) {
    int r = g >> 6, j4 = g & 63;
    int n = nbase + r;
    if (n < N) {
      float a0 = acc[r * 256 +   0 + j4];
      float a1 = acc[r * 256 +  64 + j4];
      float a2 = acc[r * 256 + 128 + j4];
      float a3 = acc[r * 256 + 192 + j4];
      a0 = fmaxf(a0, 0.f); a1 = fmaxf(a1, 0.f);
      a2 = fmaxf(a2, 0.f); a3 = fmaxf(a3, 0.f);
      if (OUTBF16) {
        ushort4 o; o.x = f2b(a0); o.y = f2b(a1); o.z = f2b(a2); o.w = f2b(a3);
        *(ushort4*)((u16*)outv + (size_t)n * 256 + j4 * 4) = o;
      } else {
        float4 o; o.x = a0; o.y = a1; o.z = a2; o.w = a3;
        *(float4*)((float*)outv + (size_t)n * 256 + j4 * 4) = o;
      }
    }
  }
}

// ---------------- launch ----------------

extern "C" void kernel_launch(void* const* d_in, const int* in_sizes, int n_in,
                              void* d_out, int out_size, void* d_ws, size_t ws_size,
                              hipStream_t stream) {
  const void* emb  = d_in[0];
  const int*  rows = (const int*)d_in[1];
  const int*  cols = (const int*)d_in[2];
  const void* vals = d_in[3];
  const void* W    = d_in[4];

  int N = in_sizes[0] / 256;
  int E = in_sizes[1];
  int NB = (N + RB - 1) >> RBSH;

  char* ws = (char*)d_ws;
  size_t off = 0;
  auto carve = [&](size_t bytes) -> char* {
    char* p = ws + off;
    off += (bytes + 511) & ~(size_t)511;
    return p;
  };
  int*  flag    = (int*) carve(4);
  int*  bcounts = (int*) carve((size_t)NBMAX * 4);
  int*  boffs   = (int*) carve((size_t)(NBMAX + 1) * 4);
  int*  bcursor = (int*) carve((size_t)NBMAX * 4);
  int2* pack    = (int2*)carve((size_t)E * 8);
  u16*  P       = (u16*) carve((size_t)N * 256 * 2);
  u16*  Wt      = (u16*) carve((size_t)256 * 256 * 2);
  (void)ws_size; (void)n_in; (void)out_size;

  hipMemsetAsync(bcounts, 0, (size_t)NBMAX * 4, stream);

  detect_k<<<1, 256, 0, stream>>>((const unsigned*)vals, flag);

  bhist_k<<<256, 256, 0, stream>>>(rows, bcounts, E, NB);
  bscan_k<<<1, 256, 0, stream>>>(bcounts, boffs, bcursor, NB);

  wtr_k<true ><<<256, 256, 0, stream>>>(flag, W, Wt);
  wtr_k<false><<<256, 256, 0, stream>>>(flag, W, Wt);

  int pb = (N + 63) / 64;
  proj_k<true ><<<pb, 256, 0, stream>>>(flag, emb, Wt, P, N);
  proj_k<false><<<pb, 256, 0, stream>>>(flag, emb, Wt, P, N);

  int mb = (E + MS_T - 1) / MS_T;
  ms_k<true ><<<mb, 256, 0, stream>>>(flag, rows, cols, vals, bcursor, pack, E, NB);
  ms_k<false><<<mb, 256, 0, stream>>>(flag, rows, cols, vals, bcursor, pack, E, NB);

  bagg_k<true ><<<NB, 512, 0, stream>>>(flag, P, boffs, pack, d_out, N);
  bagg_k<false><<<NB, 512, 0, stream>>>(flag, P, boffs, pack, d_out, N);
}

// Round 3
// 592.496 us; speedup vs baseline: 8.4983x; 8.4983x over previous
//
#include <hip/hip_runtime.h>
#include <stdint.h>

// GCN layer: out = relu( segment_sum(vals * emb[cols], rows) @ W )
// Reordered: out = relu( segment_sum(vals * P[cols], rows) ), P = emb @ W.
// Pipeline:
//   detect dtype -> bucket hist/scan (64-row buckets) -> Wt bf16 ->
//   P = emb@W (MFMA) -> ms_k: LDS multisplit edges into buckets (coalesced
//   run writes) -> ms2_k: per-bucket 64-bin counting sort -> exact CSR +
//   per-node offsets (no global hist/scan, no random scatter) ->
//   agg_k: one wave per node, 8 gathers in flight, ReLU, coalesced out.
// Round-2 lesson: LDS-atomic accumulation with shfl chains serializes on
// lgkmcnt drains (VALUBusy 1.9%); reverted to register aggregation.

typedef unsigned short u16;
typedef __attribute__((ext_vector_type(8))) short short8v;  // 8 bf16
typedef __attribute__((ext_vector_type(4))) float f32x4;    // MFMA C/D

#define RBSH 6
#define RB 64            // rows per bucket
#define NBMAX 2048       // supports N <= 131072
#define MS_T 4096        // edges per multisplit tile
#define MS_PT 16         // edges per thread (256 threads)

__device__ __forceinline__ float b2f(u16 u) {
  union { unsigned i; float f; } x; x.i = ((unsigned)u) << 16; return x.f;
}
__device__ __forceinline__ u16 f2b(float f) {
  union { unsigned i; float f; } x; x.f = f;
  unsigned r = x.i + 0x7fffu + ((x.i >> 16) & 1u);
  return (u16)(r >> 16);
}

// ---- dtype detect: adj_vals ~ U[0,1). As f32 words, low16 uniform
// (>=0x3F80 ~75%). As packed bf16 pairs, low16 is bf16 in [0,1) -> <0x3F80.
__global__ void detect_k(const unsigned* __restrict__ valsw, int* __restrict__ flag) {
  __shared__ int cnt;
  if (threadIdx.x == 0) cnt = 0;
  __syncthreads();
  int c = 0;
  for (int i = threadIdx.x; i < 4096; i += 256) {
    unsigned w = valsw[i];
    if ((w & 0xFFFFu) >= 0x3F80u) c++;
  }
  atomicAdd(&cnt, c);
  __syncthreads();
  if (threadIdx.x == 0) *flag = (cnt < 1024) ? 1 : 0;
}

// ---------------- bucket histogram (LDS-staged) ----------------
__global__ __launch_bounds__(256) void bhist_k(const int* __restrict__ rows,
                                               int* __restrict__ bcounts, int E, int NB) {
  __shared__ int h[NBMAX];
  int tid = threadIdx.x;
  for (int b = tid; b < NB; b += 256) h[b] = 0;
  __syncthreads();
  for (int i = blockIdx.x * 256 + tid; i < E; i += gridDim.x * 256)
    atomicAdd(&h[rows[i] >> RBSH], 1);
  __syncthreads();
  for (int b = tid; b < NB; b += 256) {
    int c = h[b];
    if (c) atomicAdd(&bcounts[b], c);
  }
}

// ---------------- bucket exclusive scan (1 block) ----------------
__global__ __launch_bounds__(256) void bscan_k(const int* __restrict__ bcounts,
                                               int* __restrict__ boffs,
                                               int* __restrict__ bcursor, int NB) {
  __shared__ int part[256];
  int tid = threadIdx.x;
  int K = (NB + 255) >> 8;
  int lo = tid * K, hi = lo + K;
  if (hi > NB) hi = NB;
  if (lo > NB) lo = NB;
  int s = 0;
  for (int b = lo; b < hi; ++b) s += bcounts[b];
  part[tid] = s;
  __syncthreads();
  for (int o = 1; o < 256; o <<= 1) {
    int v = (tid >= o) ? part[tid - o] : 0;
    __syncthreads();
    part[tid] += v;
    __syncthreads();
  }
  int run = part[tid] - s;  // exclusive base for this thread's range
  for (int b = lo; b < hi; ++b) {
    int c = bcounts[b];
    boffs[b] = run;
    bcursor[b] = run;
    run += c;
  }
  if (tid == 255) boffs[NB] = part[255];
}

// ---------------- multisplit pass 1: tile-sort edges by bucket in LDS ----------------
// Entry: x = col | ((row & 63) << 17)  (col < 2^17), y = f32 bits of val.
template <bool BF16>
__global__ __launch_bounds__(256) void ms_k(const int* __restrict__ flag,
                                            const int* __restrict__ rows,
                                            const int* __restrict__ cols,
                                            const void* __restrict__ valsv,
                                            int* __restrict__ bcursor,
                                            int2* __restrict__ pack, int E, int NB) {
  if (*flag != (BF16 ? 1 : 0)) return;
  __shared__ int hist[NBMAX + 1];  // becomes exclusive prefix
  __shared__ int gbase[NBMAX];
  __shared__ int part[256];
  __shared__ int2 buf[MS_T];
  __shared__ u16 brow[MS_T];
  int tid = threadIdx.x;
  int base = blockIdx.x * MS_T;

  for (int b = tid; b <= NB; b += 256) hist[b] = 0;
  __syncthreads();

  int bk[MS_PT], ofs[MS_PT], cl[MS_PT], vb[MS_PT];
#pragma unroll
  for (int i = 0; i < MS_PT; ++i) {
    int e = base + i * 256 + tid;
    if (e < E) {
      int r = rows[e];
      bk[i] = r >> RBSH;
      cl[i] = cols[e] | ((r & (RB - 1)) << 17);
      float v = BF16 ? b2f(((const u16*)valsv)[e]) : ((const float*)valsv)[e];
      vb[i] = __float_as_int(v);
      ofs[i] = atomicAdd(&hist[bk[i]], 1);
    } else {
      bk[i] = -1; ofs[i] = 0; cl[i] = 0; vb[i] = 0;
    }
  }
  __syncthreads();

  // two-level exclusive prefix of hist[0..NB) in place; hist[NB] = total
  int K = (NB + 255) >> 8;
  int lo = tid * K, hi = lo + K;
  if (hi > NB) hi = NB;
  if (lo > NB) lo = NB;
  int s = 0;
  for (int b = lo; b < hi; ++b) s += hist[b];
  part[tid] = s;
  __syncthreads();
  for (int o = 1; o < 256; o <<= 1) {
    int v = (tid >= o) ? part[tid - o] : 0;
    __syncthreads();
    part[tid] += v;
    __syncthreads();
  }
  int run = part[tid] - s;
  for (int b = lo; b < hi; ++b) {
    int c = hist[b];
    hist[b] = run;
    run += c;
  }
  if (tid == 255) hist[NB] = part[255];
  __syncthreads();

  // scatter to LDS (sorted by bucket) + reserve global ranges
#pragma unroll
  for (int i = 0; i < MS_PT; ++i) {
    if (bk[i] >= 0) {
      int slot = hist[bk[i]] + ofs[i];
      buf[slot] = make_int2(cl[i], vb[i]);
      brow[slot] = (u16)bk[i];
    }
  }
  for (int b = tid; b < NB; b += 256) {
    int c = hist[b + 1] - hist[b];
    if (c > 0) gbase[b] = atomicAdd(&bcursor[b], c);
  }
  __syncthreads();

  // coalesced-run copy out
  int tot = hist[NB];
  for (int i = tid; i < tot; i += 256) {
    int b = brow[i];
    pack[gbase[b] + (i - hist[b])] = buf[i];
  }
}

// ---------------- multisplit pass 2: per-bucket 64-bin counting sort ----------------
// Produces exact CSR (pack2 row-sorted) + per-node offsets. Dtype-independent.
__global__ __launch_bounds__(256) void ms2_k(const int* __restrict__ boffs,
                                             const int2* __restrict__ pack,
                                             int2* __restrict__ pack2,
                                             int* __restrict__ offs, int N, int NB) {
  __shared__ int bins[RB];
  __shared__ int pfx[RB];
  int b = blockIdx.x;
  int tid = threadIdx.x;
  int beg = boffs[b], end = boffs[b + 1];
  if (tid < RB) bins[tid] = 0;
  __syncthreads();
  for (int i = beg + tid; i < end; i += 256)
    atomicAdd(&bins[(pack[i].x >> 17) & (RB - 1)], 1);
  __syncthreads();
  if (tid == 0) {
    int run = 0;
    for (int r = 0; r < RB; ++r) { int c = bins[r]; pfx[r] = run; run += c; }
  }
  __syncthreads();
  if (tid < RB) {
    int n = b * RB + tid;
    if (n < N) offs[n] = beg + pfx[tid];
    bins[tid] = pfx[tid];  // cursors
  }
  if (b == NB - 1 && tid == 0) offs[N] = end;
  __syncthreads();
  for (int i = beg + tid; i < end; i += 256) {
    int2 q = pack[i];
    int r = (q.x >> 17) & (RB - 1);
    int p = atomicAdd(&bins[r], 1);
    pack2[beg + p] = q;
  }
}

// ---------------- W -> bf16, transposed: Wt[n][k] = W[k][n] ----------------
template <bool BF16>
__global__ void wtr_k(const int* __restrict__ flag, const void* __restrict__ Wv,
                      u16* __restrict__ Wt) {
  if (*flag != (BF16 ? 1 : 0)) return;
  int i = blockIdx.x * 256 + threadIdx.x;  // 65536 total
  int n = i >> 8, k = i & 255;
  float w = BF16 ? b2f(((const u16*)Wv)[k * 256 + n]) : ((const float*)Wv)[k * 256 + n];
  Wt[n * 256 + k] = f2b(w);
}

// ---------------- P = emb @ W via MFMA bf16 (verified) ----------------
template <bool BF16>
__global__ __launch_bounds__(256) void proj_k(const int* __restrict__ flag,
                                              const void* __restrict__ embv,
                                              const u16* __restrict__ Wt,
                                              u16* __restrict__ P, int N) {
  if (*flag != (BF16 ? 1 : 0)) return;
  int wave = threadIdx.x >> 6, lane = threadIdx.x & 63;
  int lr = lane & 15, lq = lane >> 4;
  int m0 = blockIdx.x * 64;
  int n0 = wave * 64;

  f32x4 acc[4][4];
#pragma unroll
  for (int mi = 0; mi < 4; ++mi)
#pragma unroll
    for (int ni = 0; ni < 4; ++ni) acc[mi][ni] = (f32x4)0.f;

  int arow[4];
#pragma unroll
  for (int mi = 0; mi < 4; ++mi) {
    int r = m0 + mi * 16 + lr;
    arow[mi] = r < N ? r : N - 1;
  }

  for (int ks = 0; ks < 8; ++ks) {
    int kb = ks * 32 + lq * 8;
    short8v a[4], b[4];
#pragma unroll
    for (int mi = 0; mi < 4; ++mi) {
      if (BF16) {
        a[mi] = *(const short8v*)((const u16*)embv + (size_t)arow[mi] * 256 + kb);
      } else {
        const float* p = (const float*)embv + (size_t)arow[mi] * 256 + kb;
        float4 x = *(const float4*)p;
        float4 y = *(const float4*)(p + 4);
        short8v t;
        t[0] = (short)f2b(x.x); t[1] = (short)f2b(x.y);
        t[2] = (short)f2b(x.z); t[3] = (short)f2b(x.w);
        t[4] = (short)f2b(y.x); t[5] = (short)f2b(y.y);
        t[6] = (short)f2b(y.z); t[7] = (short)f2b(y.w);
        a[mi] = t;
      }
    }
#pragma unroll
    for (int ni = 0; ni < 4; ++ni)
      b[ni] = *(const short8v*)(Wt + (size_t)(n0 + ni * 16 + lr) * 256 + kb);
#pragma unroll
    for (int mi = 0; mi < 4; ++mi)
#pragma unroll
      for (int ni = 0; ni < 4; ++ni)
        acc[mi][ni] = __builtin_amdgcn_mfma_f32_16x16x32_bf16(a[mi], b[ni], acc[mi][ni], 0, 0, 0);
  }

#pragma unroll
  for (int mi = 0; mi < 4; ++mi) {
    int rbase = m0 + mi * 16 + lq * 4;
#pragma unroll
    for (int ni = 0; ni < 4; ++ni) {
      int col = n0 + ni * 16 + lr;
#pragma unroll
      for (int r = 0; r < 4; ++r) {
        int row = rbase + r;
        if (row < N) P[(size_t)row * 256 + col] = f2b(acc[mi][ni][r]);
      }
    }
  }
}

// ---------------- aggregation: one wave per node, gather P rows ----------------
// out[n][d] = relu( sum_{e in row n} val_e * P[col_e][d] )
// Unroll x8: 8 independent 512B row gathers in flight per wave.
template <bool OUTBF16>
__global__ __launch_bounds__(256) void agg_k(const int* __restrict__ flag,
                                             const u16* __restrict__ P,
                                             const int* __restrict__ offs,
                                             const int2* __restrict__ pack,
                                             void* __restrict__ outv, int N) {
  if (*flag != (OUTBF16 ? 1 : 0)) return;
  int wave = threadIdx.x >> 6, lane = threadIdx.x & 63;
  int node = blockIdx.x * 4 + wave;
  if (node >= N) return;
  int beg = offs[node], end = offs[node + 1];
  float a0 = 0.f, a1 = 0.f, a2 = 0.f, a3 = 0.f;
  const u16* pb = P + lane * 4;
  int j = beg;
  for (; j + 8 <= end; j += 8) {
    int2 q0 = pack[j + 0], q1 = pack[j + 1], q2 = pack[j + 2], q3 = pack[j + 3];
    int2 q4 = pack[j + 4], q5 = pack[j + 5], q6 = pack[j + 6], q7 = pack[j + 7];
    ushort4 e0 = *(const ushort4*)(pb + (size_t)(q0.x & 0x1FFFF) * 256);
    ushort4 e1 = *(const ushort4*)(pb + (size_t)(q1.x & 0x1FFFF) * 256);
    ushort4 e2 = *(const ushort4*)(pb + (size_t)(q2.x & 0x1FFFF) * 256);
    ushort4 e3 = *(const ushort4*)(pb + (size_t)(q3.x & 0x1FFFF) * 256);
    ushort4 e4 = *(const ushort4*)(pb + (size_t)(q4.x & 0x1FFFF) * 256);
    ushort4 e5 = *(const ushort4*)(pb + (size_t)(q5.x & 0x1FFFF) * 256);
    ushort4 e6 = *(const ushort4*)(pb + (size_t)(q6.x & 0x1FFFF) * 256);
    ushort4 e7 = *(const ushort4*)(pb + (size_t)(q7.x & 0x1FFFF) * 256);
    float v0 = __int_as_float(q0.y), v1 = __int_as_float(q1.y);
    float v2 = __int_as_float(q2.y), v3 = __int_as_float(q3.y);
    float v4 = __int_as_float(q4.y), v5 = __int_as_float(q5.y);
    float v6 = __int_as_float(q6.y), v7 = __int_as_float(q7.y);
    a0 += v0 * b2f(e0.x); a1 += v0 * b2f(e0.y); a2 += v0 * b2f(e0.z); a3 += v0 * b2f(e0.w);
    a0 += v1 * b2f(e1.x); a1 += v1 * b2f(e1.y); a2 += v1 * b2f(e1.z); a3 += v1 * b2f(e1.w);
    a0 += v2 * b2f(e2.x); a1 += v2 * b2f(e2.y); a2 += v2 * b2f(e2.z); a3 += v2 * b2f(e2.w);
    a0 += v3 * b2f(e3.x); a1 += v3 * b2f(e3.y); a2 += v3 * b2f(e3.z); a3 += v3 * b2f(e3.w);
    a0 += v4 * b2f(e4.x); a1 += v4 * b2f(e4.y); a2 += v4 * b2f(e4.z); a3 += v4 * b2f(e4.w);
    a0 += v5 * b2f(e5.x); a1 += v5 * b2f(e5.y); a2 += v5 * b2f(e5.z); a3 += v5 * b2f(e5.w);
    a0 += v6 * b2f(e6.x); a1 += v6 * b2f(e6.y); a2 += v6 * b2f(e6.z); a3 += v6 * b2f(e6.w);
    a0 += v7 * b2f(e7.x); a1 += v7 * b2f(e7.y); a2 += v7 * b2f(e7.z); a3 += v7 * b2f(e7.w);
  }
  for (; j < end; ++j) {
    int2 q = pack[j];
    float v = __int_as_float(q.y);
    ushort4 e = *(const ushort4*)(pb + (size_t)(q.x & 0x1FFFF) * 256);
    a0 += v * b2f(e.x); a1 += v * b2f(e.y); a2 += v * b2f(e.z); a3 += v * b2f(e.w);
  }
  a0 = fmaxf(a0, 0.f); a1 = fmaxf(a1, 0.f);
  a2 = fmaxf(a2, 0.f); a3 = fmaxf(a3, 0.f);
  if (OUTBF16) {
    ushort4 o; o.x = f2b(a0); o.y = f2b(a1); o.z = f2b(a2); o.w = f2b(a3);
    *(ushort4*)((u16*)outv + (size_t)node * 256 + lane * 4) = o;
  } else {
    float4 o; o.x = a0; o.y = a1; o.z = a2; o.w = a3;
    *(float4*)((float*)outv + (size_t)node * 256 + lane * 4) = o;
  }
}

// ---------------- launch ----------------

extern "C" void kernel_launch(void* const* d_in, const int* in_sizes, int n_in,
                              void* d_out, int out_size, void* d_ws, size_t ws_size,
                              hipStream_t stream) {
  const void* emb  = d_in[0];
  const int*  rows = (const int*)d_in[1];
  const int*  cols = (const int*)d_in[2];
  const void* vals = d_in[3];
  const void* W    = d_in[4];

  int N = in_sizes[0] / 256;
  int E = in_sizes[1];
  int NB = (N + RB - 1) >> RBSH;

  char* ws = (char*)d_ws;
  size_t off = 0;
  auto carve = [&](size_t bytes) -> char* {
    char* p = ws + off;
    off += (bytes + 511) & ~(size_t)511;
    return p;
  };
  int*  flag    = (int*) carve(4);
  int*  bcounts = (int*) carve((size_t)NBMAX * 4);
  int*  boffs   = (int*) carve((size_t)(NBMAX + 1) * 4);
  int*  bcursor = (int*) carve((size_t)NBMAX * 4);
  int*  offs    = (int*) carve((size_t)(N + 1) * 4);
  int2* pack    = (int2*)carve((size_t)E * 8);
  int2* pack2   = (int2*)carve((size_t)E * 8);
  u16*  P       = (u16*) carve((size_t)N * 256 * 2);
  u16*  Wt      = (u16*) carve((size_t)256 * 256 * 2);
  (void)ws_size; (void)n_in; (void)out_size;

  hipMemsetAsync(bcounts, 0, (size_t)NBMAX * 4, stream);

  detect_k<<<1, 256, 0, stream>>>((const unsigned*)vals, flag);

  bhist_k<<<256, 256, 0, stream>>>(rows, bcounts, E, NB);
  bscan_k<<<1, 256, 0, stream>>>(bcounts, boffs, bcursor, NB);

  wtr_k<true ><<<256, 256, 0, stream>>>(flag, W, Wt);
  wtr_k<false><<<256, 256, 0, stream>>>(flag, W, Wt);

  int pb = (N + 63) / 64;
  proj_k<true ><<<pb, 256, 0, stream>>>(flag, emb, Wt, P, N);
  proj_k<false><<<pb, 256, 0, stream>>>(flag, emb, Wt, P, N);

  int mb = (E + MS_T - 1) / MS_T;
  ms_k<true ><<<mb, 256, 0, stream>>>(flag, rows, cols, vals, bcursor, pack, E, NB);
  ms_k<false><<<mb, 256, 0, stream>>>(flag, rows, cols, vals, bcursor, pack, E, NB);

  ms2_k<<<NB, 256, 0, stream>>>(boffs, pack, pack2, offs, N, NB);

  int ab = (N + 3) / 4;
  agg_k<true ><<<ab, 256, 0, stream>>>(flag, P, offs, pack2, d_out, N);
  agg_k<false><<<ab, 256, 0, stream>>>(flag, P, offs, pack2, d_out, N);
}